// Round 1
// 69.500 us; speedup vs baseline: 1.0047x; 1.0047x over previous
//
#include <hip/hip_runtime.h>
#include <math.h>

#define NN 8192
#define JT 256                         // j-tile width = block size
#define IC 64                          // i-chunk per block
#define NJT (NN / JT)                  // 32 j-tiles
#define NBLOCKS (2 * NJT * (NJT + 1))  // 2112 blocks
#define ALPHA_C 3.0f
#define MIN_DIFF_C 0.1f
#define LOG2E 1.44269504088896340736f
#define LN2   0.69314718055994530942f

// R6 structure (best measured). R8 change: eliminate v_exp_f32 from the
// inner loop. 2^{-(pi-pj)*log2e*sgn(dt)} factors into products of
// per-element exponentials E=2^{p*log2e}, I=2^{-p*log2e} computed ONCE at
// staging (64 trans/block, hoisted from the 64-iter loop):
//   dt>0 -> e = Ej*Ii ; dt<0 -> e = Ei*Ij
// cmp+2*cndmask+mul (4 VALU) replaces fma+and+xor+exp (4 VALU) -> same
// VALU count, trans per pair 2 -> 1 (only v_log_f32 remains).
// Range: |p| < ~4.5 -> E,I in [2^-6.5, 2^6.5], e <= ~2^13: no overflow,
// product error ~3ulp -> ~1e-6 on the final scalar (well inside tol).
// Keep unroll 4: launch_bounds(256,8) caps VGPRs at 64 (R2: unroll 8
// spilled, 23 MB WRITE_SIZE). LDS reads stay uniform-address broadcast
// (conflict-free), now 3x ds_read_b128 per 4 bodies (T, E, I).

#define PAIR_BODY(TV, EV, IV, VEXTRA)                                      \
    {                                                                      \
        const float dt  = (TV) - tjv;                  /* v_sub */         \
        const bool  neg = dt < 0.0f;                   /* v_cmp */         \
        const float ea  = neg ? (EV) : ej;             /* v_cndmask */     \
        const float eb  = neg ? ijv : (IV);            /* v_cndmask */     \
        const float e   = ea * eb;                     /* v_mul */         \
        const float lg  = __builtin_amdgcn_logf(1.0f + e); /* add+trans */ \
        const float adt = fabsf(dt);                   /* v_and */         \
        const bool valid = (VEXTRA) && (adt > MIN_DIFF_C); /* v_cmp */     \
        s = fmaf(valid ? adt : 0.0f, lg, s);           /* cndmask + fma */ \
        cnt += (unsigned int)__popcll(__ballot(valid)); /* SALU */         \
    }

__global__ __launch_bounds__(256, 8) void pair_kernel(
    const float* __restrict__ pred, const float* __restrict__ targ,
    float4* __restrict__ parts) {
    const int b = blockIdx.x;
    // decode b -> (t, ic): blocks before j-tile t = 2*t*(t+1)
    int t = (int)((sqrt(1.0 + 2.0 * (double)b) - 1.0) * 0.5);
    while (2 * (t + 1) * (t + 2) <= b) ++t;
    while (2 * t * (t + 1) > b) --t;
    const int ic = b - 2 * t * (t + 1);
    const int j0 = t * JT;
    const int i0 = ic * IC;
    const int tid = threadIdx.x;
    const int j = j0 + tid;

    // issue ALL global loads first so their latency overlaps the barrier
    const float pj  = pred[j];
    const float tjv = targ[j];
    float stage_p = 0.0f, stage_t = 0.0f;
    if (tid < IC) { stage_p = pred[i0 + tid]; stage_t = targ[i0 + tid]; }

    __shared__ __align__(16) float sT[IC];
    __shared__ __align__(16) float sE[IC];  // 2^{+p*log2e}
    __shared__ __align__(16) float sI[IC];  // 2^{-p*log2e}
    if (tid < IC) {
        const float pl = stage_p * LOG2E;
        sT[tid] = stage_t;
        sE[tid] = __builtin_amdgcn_exp2f(pl);
        sI[tid] = __builtin_amdgcn_exp2f(-pl);
    }
    __syncthreads();

    const float pjl = pj * LOG2E;
    const float ej  = __builtin_amdgcn_exp2f(pjl);
    const float ijv = __builtin_amdgcn_exp2f(-pjl);

    float s = 0.0f;        // sum conf * log2(1+e)   (ln2 applied later)
    float r = 0.0f;        // regression partial
    unsigned int cnt = 0;  // wave-total masked-pair count (wave-uniform)

    const bool diag = (ic >= 4 * t);

    if (!diag) {
        #pragma unroll 4
        for (int ii = 0; ii < IC; ii += 4) {
            const float4 t4 = *(const float4*)&sT[ii];  // ds_read_b128
            const float4 e4 = *(const float4*)&sE[ii];  // ds_read_b128
            const float4 i4 = *(const float4*)&sI[ii];  // ds_read_b128
            PAIR_BODY(t4.x, e4.x, i4.x, true)
            PAIR_BODY(t4.y, e4.y, i4.y, true)
            PAIR_BODY(t4.z, e4.z, i4.z, true)
            PAIR_BODY(t4.w, e4.w, i4.w, true)
        }
    } else {
        #pragma unroll 4
        for (int ii = 0; ii < IC; ii += 4) {
            const float4 t4 = *(const float4*)&sT[ii];
            const float4 e4 = *(const float4*)&sE[ii];
            const float4 i4 = *(const float4*)&sI[ii];
            const int ib = i0 + ii;
            PAIR_BODY(t4.x, e4.x, i4.x, (ib + 0) < j)
            PAIR_BODY(t4.y, e4.y, i4.y, (ib + 1) < j)
            PAIR_BODY(t4.z, e4.z, i4.z, (ib + 2) < j)
            PAIR_BODY(t4.w, e4.w, i4.w, (ib + 3) < j)
        }
        // exactly one diagonal chunk per j-tile carries the MSE term
        if (ic == 4 * t + 3) { const float d = pj - tjv; r = d * d; }
    }

    // ---- block reduction: shuffle s (and r only on diag blocks) ----
    #pragma unroll
    for (int off = 32; off > 0; off >>= 1) s += __shfl_down(s, off, 64);
    if (diag) {
        #pragma unroll
        for (int off = 32; off > 0; off >>= 1) r += __shfl_down(r, off, 64);
    }
    __shared__ float red_s[4], red_c[4], red_r[4];
    const int wave = tid >> 6;
    const int lane = tid & 63;
    if (lane == 0) { red_s[wave] = s; red_c[wave] = (float)cnt; red_r[wave] = r; }
    __syncthreads();
    if (tid == 0) {
        parts[b] = make_float4(red_s[0] + red_s[1] + red_s[2] + red_s[3],
                               red_c[0] + red_c[1] + red_c[2] + red_c[3],
                               red_r[0] + red_r[1] + red_r[2] + red_r[3], 0.0f);
    }
}

__global__ __launch_bounds__(256) void finalize_kernel(
    const float4* __restrict__ parts, float* __restrict__ out) {
    float s = 0.0f, c = 0.0f, r = 0.0f;
    for (int i = threadIdx.x; i < NBLOCKS; i += 256) {
        const float4 v = parts[i];
        s += v.x; c += v.y; r += v.z;
    }
    #pragma unroll
    for (int off = 32; off > 0; off >>= 1) {
        s += __shfl_down(s, off, 64);
        c += __shfl_down(c, off, 64);
        r += __shfl_down(r, off, 64);
    }
    __shared__ float red_s[4], red_c[4], red_r[4];
    const int wave = threadIdx.x >> 6;
    const int lane = threadIdx.x & 63;
    if (lane == 0) { red_s[wave] = s; red_c[wave] = c; red_r[wave] = r; }
    __syncthreads();
    if (threadIdx.x == 0) {
        const float fs = red_s[0] + red_s[1] + red_s[2] + red_s[3];
        const float fc = red_c[0] + red_c[1] + red_c[2] + red_c[3];
        const float fr = red_r[0] + red_r[1] + red_r[2] + red_r[3];
        const float reg = fr / (float)NN;
        const float pm  = LN2 * fs / fmaxf(fc, 1.0f);
        out[0] = (fc > 0.0f) ? (reg + ALPHA_C * pm) : reg;
    }
}

extern "C" void kernel_launch(void* const* d_in, const int* in_sizes, int n_in,
                              void* d_out, int out_size, void* d_ws, size_t ws_size,
                              hipStream_t stream) {
    const float* pred = (const float*)d_in[0];
    const float* targ = (const float*)d_in[1];
    float* out = (float*)d_out;
    float4* parts = (float4*)d_ws;   // NBLOCKS * 16 B = 33,792 B

    pair_kernel<<<NBLOCKS, 256, 0, stream>>>(pred, targ, parts);
    finalize_kernel<<<1, 256, 0, stream>>>(parts, out);
}